// Round 3
// baseline (74.800 us; speedup 1.0000x reference)
//
#include <hip/hip_runtime.h>
#include <math.h>

typedef unsigned int u32;
typedef unsigned short u16;
typedef unsigned char u8;
typedef int i32x4 __attribute__((ext_vector_type(4)));
typedef int i32x16 __attribute__((ext_vector_type(16)));

#if __has_builtin(__builtin_amdgcn_mfma_i32_32x32x32_i8)
#define HAS_MFMA_I8 1
#else
#define HAS_MFMA_I8 0
#endif

__device__ __forceinline__ u32 sad8(u32 a, u32 b, u32 c){
#if __has_builtin(__builtin_amdgcn_sad_u8)
    return __builtin_amdgcn_sad_u8(a, b, c);
#else
    u32 s = c;
#pragma unroll
    for (int k = 0; k < 4; ++k){
        int av = (int)((a >> (8*k)) & 255u), bv = (int)((b >> (8*k)) & 255u);
        s += (u32)(av > bv ? av - bv : bv - av);
    }
    return s;
#endif
}

__device__ __forceinline__ u32 hsum16(u32 x, u32 c){ return c + (x & 0xFFFFu) + (x >> 16); }

#if !HAS_MFMA_I8
__device__ __forceinline__ int sdot4(u32 a, u32 b, int c){
#if __has_builtin(__builtin_amdgcn_sdot4)
    return __builtin_amdgcn_sdot4((int)a, (int)b, c, false);
#else
    int s = c;
#pragma unroll
    for (int k = 0; k < 4; ++k){
        int av = (int)(signed char)((a >> (8*k)) & 255u);
        int bv = (int)(signed char)((b >> (8*k)) & 255u);
        s += av * bv;
    }
    return s;
#endif
}
#endif

// ---- R12: SINGLE kernel. prep folded into the staging phase.
// Rationale (R10/R11 counters): fused's real work models at ~6-7 us; the
// controllable ~29 us (70.9 total - 41.5 us harness poison-fill) was mostly
// structure: prep launch + prep->fused dependency gap + q8 global round-trip.
// Each block now quantizes its own 96 rows (f32 -> u8, identical math to the
// old prep) directly into the SAME LDS staging layout, and computes norms
// in-block (per-(row,wave) ssq partials via shfl_xor -> 3KB LDS corner ->
// 96-thread reduce in the epilogue). d_ws is now completely unused.
// Everything after barrier #1 (MFMA, sad loop, epilogue) is byte-identical
// to R11. #pragma unroll 2 on the staging j-loop caps in-flight f32 loads
// (~32 regs) so staging can't blow the 128-VGPR budget (R10 lesson);
// waves_per_eu(4,4) pin retained.
// LDS map (u32 words): [0,15360) staging [8 waves][96 rows][20 w] /
// epilogue overlay; [15360,16128) nlds[96][8] ssq partials;
// [16128,16224) nfin[96] final norms. 64.9 KB -> 2 blocks/CU (unchanged).
#define RS 20
#define L1S 520
__global__ __launch_bounds__(512)
__attribute__((amdgpu_waves_per_eu(4, 4)))
void fused_kernel(const float* __restrict__ z,
                  const float* __restrict__ zpr,
                  float* __restrict__ out){
    __shared__ u32 smem[16224];   // 64.9 KB
    const int t = threadIdx.x;
    const int lane = t & 63;
    const int w = t >> 6;
    const int bn = blockIdx.x & 31;
    const int bm = blockIdx.x >> 5;
    const int n_base = bn*32, m_base = bm*64;

    u32*   wbase = smem + w*1920;
    float* nlds  = (float*)(smem + 15360);   // [96][8]
    float* nfin  = (float*)(smem + 16128);   // [96]

    // ---- stage + quantize: wave w's k-slice [64w, 64w+64), 96 rows ----
    {
        const int c  = lane & 3;             // 16B column within the 64B slice
        const int r4 = lane >> 2;            // row within 16-row group
#pragma unroll 2
        for (int j = 0; j < 6; ++j){
            const int rt = j*16 + r4;        // 0..95
            const float* src = (rt < 32) ? (z   + (size_t)(n_base + rt)*512)
                                         : (zpr + (size_t)(m_base + rt - 32)*512);
            const float4* p = (const float4*)(src + 64*w + 16*c);
            u32 bw[4]; float ss = 0.f;
#pragma unroll
            for (int q = 0; q < 4; ++q){
                float4 f = p[q];
                u32 q0 = (u32)fmaf(f.x, 16.f, 128.5f) & 255u;
                u32 q1 = (u32)fmaf(f.y, 16.f, 128.5f) & 255u;
                u32 q2 = (u32)fmaf(f.z, 16.f, 128.5f) & 255u;
                u32 q3 = (u32)fmaf(f.w, 16.f, 128.5f) & 255u;
                bw[q] = q0 | (q1 << 8) | (q2 << 16) | (q3 << 24);
                const int s0 = (int)q0 - 128, s1 = (int)q1 - 128;
                const int s2 = (int)q2 - 128, s3 = (int)q3 - 128;
                ss += (float)(s0*s0 + s1*s1 + s2*s2 + s3*s3);
            }
            *(uint4*)(wbase + rt*RS + 4*c) = make_uint4(bw[0], bw[1], bw[2], bw[3]);
            // reduce ssq over the 4 c-lanes of this row-slice
            ss += __shfl_xor(ss, 1);
            ss += __shfl_xor(ss, 2);
            if (c == 0) nlds[rt*8 + w] = ss;
        }
    }

    const int tn = lane & 3, tm = lane >> 2;
    u32 acc[8][4];
#pragma unroll
    for (int i = 0; i < 8; ++i)
#pragma unroll
        for (int j = 0; j < 4; ++j) acc[i][j] = 0u;

#if HAS_MFMA_I8
    i32x16 dpacc = (i32x16)(0);
    const int mt = w & 1;          // m-tile (32 cols) for waves 0-3
    const int kh = w >> 1;         // k-half group for waves 0-3
    const int arow = lane & 31;
    const int brow = 32 + mt*32 + (lane & 31);
    const int o1 = lane >> 5;
#else
    int dpa[8][4];
#pragma unroll
    for (int i = 0; i < 8; ++i)
#pragma unroll
        for (int j = 0; j < 4; ++j) dpa[i][j] = 0;
#endif

    __syncthreads();   // barrier #1: all tiles staged + nlds written

#if HAS_MFMA_I8
    if (w < 4){
#pragma unroll
        for (int s = 0; s < 4; ++s){
            const u32* gb = smem + (kh*4 + s)*1920;
#pragma unroll
            for (int h = 0; h < 2; ++h){
                uint4 a = *(const uint4*)(gb + arow*RS + 8*h + 4*o1);
                uint4 b = *(const uint4*)(gb + brow*RS + 8*h + 4*o1);
                uint4 ax = make_uint4(a.x^0x80808080u, a.y^0x80808080u, a.z^0x80808080u, a.w^0x80808080u);
                uint4 bx = make_uint4(b.x^0x80808080u, b.y^0x80808080u, b.z^0x80808080u, b.w^0x80808080u);
                dpacc = __builtin_amdgcn_mfma_i32_32x32x32_i8(__builtin_bit_cast(i32x4, ax),
                                                              __builtin_bit_cast(i32x4, bx),
                                                              dpacc, 0, 0, 0);
            }
        }
    }
#endif

    // ---- sad hot loop: wave w's 64 k, 8n x 4m micro (av loaded in halves) ----
#pragma unroll
    for (int c = 0; c < 4; ++c){
        uint4 bv[4];
#pragma unroll
        for (int j2 = 0; j2 < 4; ++j2)
            bv[j2] = *(const uint4*)(wbase + (32 + tm + 16*j2)*RS + 4*c);
#pragma unroll
        for (int ih = 0; ih < 2; ++ih){
            uint4 av[4];
#pragma unroll
            for (int i = 0; i < 4; ++i)
                av[i] = *(const uint4*)(wbase + (tn + 4*(4*ih + i))*RS + 4*c);
#pragma unroll
            for (int i = 0; i < 4; ++i)
#pragma unroll
                for (int j2 = 0; j2 < 4; ++j2){
                    u32 s = acc[4*ih + i][j2];
                    s = sad8(av[i].x, bv[j2].x, s);
                    s = sad8(av[i].y, bv[j2].y, s);
                    s = sad8(av[i].z, bv[j2].z, s);
                    s = sad8(av[i].w, bv[j2].w, s);
                    acc[4*ih + i][j2] = s;
#if !HAS_MFMA_I8
                    int d = dpa[4*ih + i][j2];
                    d = sdot4(av[i].x^0x80808080u, bv[j2].x^0x80808080u, d);
                    d = sdot4(av[i].y^0x80808080u, bv[j2].y^0x80808080u, d);
                    d = sdot4(av[i].z^0x80808080u, bv[j2].z^0x80808080u, d);
                    d = sdot4(av[i].w^0x80808080u, bv[j2].w^0x80808080u, d);
                    dpa[4*ih + i][j2] = d;
#endif
                }
        }
    }
    __syncthreads();   // barrier #2: all staging reads done; region now dead

    // ---- epilogue (overlays staging; nlds/nfin live above it) ----
    u16*   l1b  = (u16*)smem;                  // [32 n][520] u16
    float* dpbA = (float*)(smem + 8320);       // [32][65]
    float* dpbB = (float*)(smem + 10400);      // [32][65]

    // finalize norms: 96 rows, 8 wave-partials each (exact: ints < 2^24)
    if (t < 96){
        const float4* nl = (const float4*)(nlds + t*8);
        float4 a = nl[0], b = nl[1];
        nfin[t] = ((a.x + a.y) + (a.z + a.w)) + ((b.x + b.y) + (b.z + b.w));
    }

#pragma unroll
    for (int i = 0; i < 8; ++i)
#pragma unroll
        for (int j = 0; j < 4; ++j)
            l1b[(tn + 4*i)*L1S + (tm + 16*j)*8 + w] = (u16)acc[i][j];

#if HAS_MFMA_I8
    if (w < 4){
        float* dpb = kh ? dpbB : dpbA;
        const int mcol = mt*32 + (lane & 31);
#pragma unroll
        for (int reg = 0; reg < 16; ++reg){
            const int n = (reg & 3) + 8*(reg >> 2) + 4*(lane >> 5);
            dpb[n*65 + mcol] = (float)dpacc[reg];
        }
    }
#endif
    __syncthreads();   // barrier #3

    const int m  = t >> 3;
    const int n0 = 4*(t & 7);
    float4 nz4 = *(const float4*)&nfin[n0];
    const float np = nfin[32 + m];
    const float nzv[4] = {nz4.x, nz4.y, nz4.z, nz4.w};

    float l1q[4], dpq[4];
#pragma unroll
    for (int i = 0; i < 4; ++i){
        const int n = n0 + i;
        uint4 lp = *(const uint4*)&l1b[n*L1S + m*8];
        u32 s = hsum16(lp.x, 0u); s = hsum16(lp.y, s);
        s = hsum16(lp.z, s);      s = hsum16(lp.w, s);
        l1q[i] = (float)s;
#if HAS_MFMA_I8
        dpq[i] = dpbA[n*65 + m] + dpbB[n*65 + m];
#else
        dpq[i] = 0.f;
#endif
    }

#if !HAS_MFMA_I8
    {
        float* dpf = (float*)(smem + 8320);   // [2048][2]
#pragma unroll
        for (int ph = 0; ph < 4; ++ph){
            __syncthreads();
            if ((w >> 1) == ph){
#pragma unroll
                for (int i = 0; i < 8; ++i)
#pragma unroll
                    for (int j = 0; j < 4; ++j)
                        dpf[((tn + 4*i)*64 + tm + 16*j)*2 + (w & 1)] = (float)dpa[i][j];
            }
            __syncthreads();
#pragma unroll
            for (int i = 0; i < 4; ++i){
                const int cell = (n0 + i)*64 + m;
                dpq[i] += dpf[cell*2] + dpf[cell*2 + 1];
            }
        }
    }
#endif

    float ov[12];
#pragma unroll
    for (int i = 0; i < 4; ++i){
        const float l2q = nzv[i] + np - 2.f*dpq[i];
        ov[3*i]     = l1q[i] * 0.0625f;
        ov[3*i + 1] = sqrtf(fmaxf(l2q, 0.f)) * 0.0625f;
        ov[3*i + 2] = dpq[i] * 0.00390625f;
    }
    float4* op = (float4*)(out + (((size_t)(m_base + m))*1024 + n_base + n0)*3);
    op[0] = make_float4(ov[0], ov[1], ov[2],  ov[3]);
    op[1] = make_float4(ov[4], ov[5], ov[6],  ov[7]);
    op[2] = make_float4(ov[8], ov[9], ov[10], ov[11]);
}

extern "C" void kernel_launch(void* const* d_in, const int* in_sizes, int n_in,
                              void* d_out, int out_size, void* d_ws, size_t ws_size,
                              hipStream_t stream) {
    const float* z   = (const float*)d_in[0];
    const float* zpr = (const float*)d_in[1];
    float* out = (float*)d_out;
    (void)d_ws; (void)ws_size;   // workspace no longer used

    fused_kernel<<<512, 512, 0, stream>>>(z, zpr, out);
}